// Round 1
// 646.846 us; speedup vs baseline: 1.2565x; 1.2565x over previous
//
#include <hip/hip_runtime.h>

#define NTOK 4096
#define DIN  4096
#define DOUT 4096

typedef short bf16x8 __attribute__((ext_vector_type(8)));
typedef float f32x4  __attribute__((ext_vector_type(4)));

__device__ __forceinline__ unsigned short f2bf(float f) {
    union { float f; unsigned u; } v; v.f = f;
    unsigned r = v.u + 0x7FFFu + ((v.u >> 16) & 1u);
    return (unsigned short)(r >> 16);
}

__device__ __forceinline__ void async_copy16(const void* g, void* l) {
    __builtin_amdgcn_global_load_lds(
        (const __attribute__((address_space(1))) unsigned int*)g,
        (__attribute__((address_space(3))) unsigned int*)l, 16, 0, 0);
}

// ---------------- per-row scale (fp64 for quantization-boundary fidelity) ----------------
__global__ void scale_kernel(const float* __restrict__ w, double* __restrict__ scale) {
    int row = blockIdx.x;
    const float4* wr = (const float4*)(w + (size_t)row * DIN);
    double s = 0.0;
    for (int i = threadIdx.x; i < DIN / 4; i += 256) {
        float4 v = wr[i];
        s += (double)fabsf(v.x) + (double)fabsf(v.y) + (double)fabsf(v.z) + (double)fabsf(v.w);
    }
    for (int o = 32; o > 0; o >>= 1) s += __shfl_down(s, o);
    __shared__ double part[4];
    int wave = threadIdx.x >> 6, lane = threadIdx.x & 63;
    if (lane == 0) part[wave] = s;
    __syncthreads();
    if (threadIdx.x == 0) {
        double m = (part[0] + part[1] + part[2] + part[3]) * (1.0 / DIN);
        scale[row] = fmax(m, 1e-5);
    }
}

// ---------------- build w_eff bf16 ----------------
__global__ void weff_kernel(const float* __restrict__ w, const float* __restrict__ fast,
                            const float* __restrict__ slow, const double* __restrict__ scale,
                            unsigned short* __restrict__ weff) {
    int i4 = blockIdx.x * 256 + threadIdx.x;   // float4 index, 4194304 total
    double sc = scale[i4 >> 10];
    float4 wv = ((const float4*)w)[i4];
    float4 fv = ((const float4*)fast)[i4];
    float4 sv = ((const float4*)slow)[i4];
    ushort4 o;
    o.x = f2bf((float)(fmin(fmax(rint((double)wv.x / sc), -1.0), 1.0) * sc + 0.1 * (double)fv.x + 0.05 * (double)sv.x));
    o.y = f2bf((float)(fmin(fmax(rint((double)wv.y / sc), -1.0), 1.0) * sc + 0.1 * (double)fv.y + 0.05 * (double)sv.y));
    o.z = f2bf((float)(fmin(fmax(rint((double)wv.z / sc), -1.0), 1.0) * sc + 0.1 * (double)fv.z + 0.05 * (double)sv.z));
    o.w = f2bf((float)(fmin(fmax(rint((double)wv.w / sc), -1.0), 1.0) * sc + 0.1 * (double)fv.w + 0.05 * (double)sv.w));
    ((ushort4*)weff)[i4] = o;
}

// ---------------- x -> x_bf16 (row-major) + xT bf16 ----------------
__global__ void transpose_kernel(const float* __restrict__ x, unsigned short* __restrict__ xbf,
                                 unsigned short* __restrict__ xT) {
    __shared__ unsigned short tile[32][33];
    int bi = blockIdx.y, bj = blockIdx.x;
    int tx = threadIdx.x, ty = threadIdx.y;  // (32, 8)
    #pragma unroll
    for (int s = 0; s < 4; ++s) {
        unsigned short b = f2bf(x[(size_t)(bi * 32 + ty + s * 8) * DIN + bj * 32 + tx]);
        tile[ty + s * 8][tx] = b;
        xbf[(size_t)(bi * 32 + ty + s * 8) * DIN + bj * 32 + tx] = b;
    }
    __syncthreads();
    #pragma unroll
    for (int s = 0; s < 4; ++s)
        xT[(size_t)(bj * 32 + ty + s * 8) * NTOK + bi * 32 + tx] = tile[tx][ty + s * 8];
}

// =====================================================================================
// 256x256 / BK=64 / 8-wave / 8-phase GEMM mainloop (m201-style template, plain HIP).
// NT layout: C[row, col] = sum_k A[row, k] * B[col, k], both A,B bf16 row-major ld=4096.
// LDS: A dbuf [2][256][64] @ 0, B dbuf [2][256][64] @ 32768 ushorts (128 KiB).
// Bank swizzle: 16B chunk at (row, cc) stored at slot cc ^ (row & 7); applied to the
// per-lane GLOBAL source (global_load_lds dest stays linear) and to ds_read addresses.
// vmcnt discipline: counted vmcnt(4) at phases 4 and 8 only; vmcnt(0) only last iter.
// =====================================================================================
#define LDHALF 8192          // ushorts per 128-row half-tile
#define LDBUF  16384         // ushorts per 256-row dbuf buffer
#define B_BASE 32768         // ushort offset of B region

#define BAR()   __builtin_amdgcn_s_barrier()
#define LGKM0() do { asm volatile("s_waitcnt lgkmcnt(0)" ::: "memory"); \
                     __builtin_amdgcn_sched_barrier(0); } while (0)
#define VM(n_)  asm volatile("s_waitcnt vmcnt(" #n_ ")" ::: "memory")

#define STG(gp_, kt_, h_, buf_, reg_) do { \
    const unsigned short* gb_ = (gp_) + ((size_t)(h_) * 128) * 4096 + (size_t)(kt_) * 64; \
    async_copy16(gb_ + soff0, lds + (reg_) + (buf_) * LDBUF + (h_) * LDHALF + tid * 8); \
    async_copy16(gb_ + soff1, lds + (reg_) + (buf_) * LDBUF + (h_) * LDHALF + 4096 + tid * 8); \
  } while (0)

#define LDA4(rh_, buf_) { \
    _Pragma("unroll") for (int f = 0; f < 4; ++f) { \
      int ro_ = (buf_) * LDBUF + aOff + ((rh_) * 64 + f * 16) * 64; \
      a[f][0] = *(const bf16x8*)&lds[ro_ + swz0]; \
      a[f][1] = *(const bf16x8*)&lds[ro_ + swz1]; \
    } }

#define LDB2(bn_, ch_, buf_) { \
    _Pragma("unroll") for (int j = 0; j < 2; ++j) { \
      int ro_ = B_BASE + (buf_) * LDBUF + bOff + ((ch_) * 32 + j * 16) * 64; \
      bn_[j][0] = *(const bf16x8*)&lds[ro_ + swz0]; \
      bn_[j][1] = *(const bf16x8*)&lds[ro_ + swz1]; \
    } }

#define MFMAQ(rh_, bn_, ch_) { \
    _Pragma("unroll") for (int f = 0; f < 4; ++f) \
    _Pragma("unroll") for (int j = 0; j < 2; ++j) { \
      acc[(rh_)*4+f][(ch_)*2+j] = __builtin_amdgcn_mfma_f32_16x16x32_bf16( \
          a[f][0], bn_[j][0], acc[(rh_)*4+f][(ch_)*2+j], 0, 0, 0); \
      acc[(rh_)*4+f][(ch_)*2+j] = __builtin_amdgcn_mfma_f32_16x16x32_bf16( \
          a[f][1], bn_[j][1], acc[(rh_)*4+f][(ch_)*2+j], 0, 0, 0); \
    } }

__device__ __forceinline__ void gemm256_loop(const unsigned short* __restrict__ gAb,
                                             const unsigned short* __restrict__ gBb,
                                             unsigned short* lds, f32x4 (&acc)[8][4],
                                             int tid) {
    const int l16 = tid & 15, q = (tid >> 4) & 3, wid = tid >> 6;
    const int wr = wid >> 2, wc = wid & 3;
    const int swz0 = ((q) ^ (l16 & 7)) << 3;        // ks=0: cc = q
    const int swz1 = ((4 + q) ^ (l16 & 7)) << 3;    // ks=1: cc = 4+q
    const int aOff = (wr * 128 + l16) * 64;
    const int bOff = (wc * 64 + l16) * 64;
    // staging source offsets: chunk d = p*512+tid; row = d>>3, slot s = d&7,
    // logical chunk cc = s ^ (row&7)  (involution matches read-side XOR)
    const int soff0 = (tid >> 3) * 4096 + (((tid & 7) ^ ((tid >> 3) & 7)) << 3);
    const int soff1 = soff0 + 64 * 4096;

    bf16x8 a[4][2], b0[2][2], b1[2][2];
    #pragma unroll
    for (int i = 0; i < 8; ++i)
        #pragma unroll
        for (int j = 0; j < 4; ++j) acc[i][j] = (f32x4){0.f, 0.f, 0.f, 0.f};

    // prologue: kt0 (buf0) fully, kt1.B halves (buf1); allow kt1.B in flight
    STG(gAb, 0, 0, 0, 0);       STG(gAb, 0, 1, 0, 0);
    STG(gBb, 0, 0, 0, B_BASE);  STG(gBb, 0, 1, 0, B_BASE);
    STG(gBb, 1, 0, 1, B_BASE);  STG(gBb, 1, 1, 1, B_BASE);
    VM(4);
    BAR();

    #pragma unroll 1
    for (int i = 0; i < 32; ++i) {          // K-tiles 2i (buf0), 2i+1 (buf1)
        const bool nl = (i < 31);
        // ---- P1: Q(rh0,ch0) of kt ---- stage (kt+1).A0 -> buf1
        LDA4(0, 0); LDB2(b0, 0, 0);
        STG(gAb, 2 * i + 1, 0, 1, 0);
        BAR(); LGKM0();
        __builtin_amdgcn_s_setprio(1); MFMAQ(0, b0, 0); __builtin_amdgcn_s_setprio(0);
        BAR();
        // ---- P2: Q(rh0,ch1) ---- stage (kt+1).A1 -> buf1
        LDB2(b1, 1, 0);
        STG(gAb, 2 * i + 1, 1, 1, 0);
        BAR(); LGKM0();
        __builtin_amdgcn_s_setprio(1); MFMAQ(0, b1, 1); __builtin_amdgcn_s_setprio(0);
        BAR();
        // ---- P3: Q(rh1,ch0) ---- stage (kt+2).B0 -> buf0
        LDA4(1, 0);
        if (nl) STG(gBb, 2 * i + 2, 0, 0, B_BASE);
        BAR(); LGKM0();
        __builtin_amdgcn_s_setprio(1); MFMAQ(1, b0, 0); __builtin_amdgcn_s_setprio(0);
        BAR();
        // ---- P4: Q(rh1,ch1) ---- stage (kt+2).B1 -> buf0; K-tile boundary vmcnt
        if (nl) STG(gBb, 2 * i + 2, 1, 0, B_BASE);
        BAR();
        __builtin_amdgcn_s_setprio(1); MFMAQ(1, b1, 1); __builtin_amdgcn_s_setprio(0);
        if (nl) { VM(4); } else { VM(0); }   // last iter: stages skipped -> full drain
        BAR();
        // ---- P5: Q(rh0,ch0) of kt+1 (buf1) ---- stage (kt+2).A0 -> buf0
        LDA4(0, 1); LDB2(b0, 0, 1);
        if (nl) STG(gAb, 2 * i + 2, 0, 0, 0);
        BAR(); LGKM0();
        __builtin_amdgcn_s_setprio(1); MFMAQ(0, b0, 0); __builtin_amdgcn_s_setprio(0);
        BAR();
        // ---- P6 ---- stage (kt+2).A1 -> buf0
        LDB2(b1, 1, 1);
        if (nl) STG(gAb, 2 * i + 2, 1, 0, 0);
        BAR(); LGKM0();
        __builtin_amdgcn_s_setprio(1); MFMAQ(0, b1, 1); __builtin_amdgcn_s_setprio(0);
        BAR();
        // ---- P7 ---- stage (kt+3).B0 -> buf1
        LDA4(1, 1);
        if (nl) STG(gBb, 2 * i + 3, 0, 1, B_BASE);
        BAR(); LGKM0();
        __builtin_amdgcn_s_setprio(1); MFMAQ(1, b0, 0); __builtin_amdgcn_s_setprio(0);
        BAR();
        // ---- P8 ---- stage (kt+3).B1 -> buf1; K-tile boundary vmcnt
        if (nl) STG(gBb, 2 * i + 3, 1, 1, B_BASE);
        BAR();
        __builtin_amdgcn_s_setprio(1); MFMAQ(1, b1, 1); __builtin_amdgcn_s_setprio(0);
        if (nl) VM(4);
        BAR();
    }
}

// ---------------- GEMM1: y[n,m] = sum_k xbf[n,k]*weff[m,k]; epilogue y fp32 + relu^T bf16 ----
__launch_bounds__(512, 2)
__global__ void gemm1_kernel(const unsigned short* __restrict__ xbf, const unsigned short* __restrict__ weff,
                             float* __restrict__ y, unsigned short* __restrict__ yactT) {
    extern __shared__ unsigned short lds[];
    int tid = threadIdx.x;
    int bid = blockIdx.x;
    int swz = ((bid & 7) << 5) | (bid >> 3);        // XCD-aware bijective swizzle (256 wgs)
    int rowBase = (swz >> 4) * 256;                  // n
    int colBase = (swz & 15) * 256;                  // m

    f32x4 acc[8][4];
    gemm256_loop(xbf + (size_t)rowBase * 4096, weff + (size_t)colBase * 4096, lds, acc, tid);

    const int l16 = tid & 15, q = (tid >> 4) & 3, wid = tid >> 6;
    const int wr = wid >> 2, wc = wid & 3;

    // y fp32 store + relu-transpose staged in LDS (256 x 264-pad, reuses staging LDS)
    const int TSTR = 264;
    #pragma unroll
    for (int fi = 0; fi < 8; ++fi) {
        int rl = wr * 128 + fi * 16 + q * 4;
        #pragma unroll
        for (int fj = 0; fj < 4; ++fj) {
            int cl = wc * 64 + fj * 16 + l16;
            #pragma unroll
            for (int r = 0; r < 4; ++r) {
                float v = acc[fi][fj][r];
                y[(size_t)(rowBase + rl + r) * DOUT + colBase + cl] = v;
                lds[cl * TSTR + rl + r] = f2bf(fmaxf(v, 0.0f));
            }
        }
    }
    __syncthreads();
    // coalesced write of yactT[m][n]: 8 threads per m-row, 4 passes of 64 rows
    int mrow = tid >> 3, cchunk = tid & 7;
    #pragma unroll
    for (int pass = 0; pass < 4; ++pass) {
        int mm = pass * 64 + mrow;
        const uint4* src = (const uint4*)(lds + mm * TSTR);
        uint4* dst = (uint4*)(yactT + (size_t)(colBase + mm) * NTOK + rowBase);
        #pragma unroll
        for (int g = 0; g < 4; ++g) dst[cchunk + g * 8] = src[cchunk + g * 8];
    }
}

// ---------------- GEMM2: nf_pre[m,k] = 0.95*fast + 0.05*(sum_n yactT[m,n]*xT[k,n])/4096 -----
__launch_bounds__(512, 2)
__global__ void gemm2_kernel(const unsigned short* __restrict__ yactT, const unsigned short* __restrict__ xT,
                             const float* __restrict__ fast, float* __restrict__ outFast,
                             float* __restrict__ norm2) {
    extern __shared__ unsigned short lds[];
    int tid = threadIdx.x;
    int bid = blockIdx.x;
    int swz = ((bid & 7) << 5) | (bid >> 3);
    int rowBase = (swz >> 4) * 256;                  // m
    int colBase = (swz & 15) * 256;                  // k

    f32x4 acc[8][4];
    gemm256_loop(yactT + (size_t)rowBase * 4096, xT + (size_t)colBase * 4096, lds, acc, tid);

    const int l16 = tid & 15, q = (tid >> 4) & 3, wid = tid >> 6;
    const int wr = wid >> 2, wc = wid & 3;

    float lsum = 0.f;
    #pragma unroll
    for (int fi = 0; fi < 8; ++fi) {
        int rg = rowBase + wr * 128 + fi * 16 + q * 4;
        #pragma unroll
        for (int fj = 0; fj < 4; ++fj) {
            int cg = colBase + wc * 64 + fj * 16 + l16;
            #pragma unroll
            for (int r = 0; r < 4; ++r) {
                float d = acc[fi][fj][r] * (1.0f / 4096.0f);
                float nf = 0.95f * fast[(size_t)(rg + r) * DIN + cg] + 0.05f * d;
                outFast[(size_t)(rg + r) * DIN + cg] = nf;
                lsum += nf * nf;
            }
        }
    }
    for (int o = 32; o > 0; o >>= 1) lsum += __shfl_down(lsum, o);
    float* redbuf = (float*)lds;
    __syncthreads();
    if ((tid & 63) == 0) redbuf[tid >> 6] = lsum;
    __syncthreads();
    if (tid == 0) {
        float s = 0.f;
        #pragma unroll
        for (int k2 = 0; k2 < 8; ++k2) s += redbuf[k2];
        atomicAdd(norm2, s);
    }
}

// ---------------- finalize: homeostatic rescale + slow update ----------------
__global__ void finalize_kernel(const float* __restrict__ slow, float* __restrict__ outFast,
                                float* __restrict__ outSlow, const float* __restrict__ norm2) {
    float n = sqrtf(*norm2);
    float s = (n > 5.0f) ? 5.0f / (n + 1e-6f) : 1.0f;
    int i = blockIdx.x * 256 + threadIdx.x;          // float4 index
    float4 f = ((const float4*)outFast)[i];
    f.x *= s; f.y *= s; f.z *= s; f.w *= s;
    ((float4*)outFast)[i] = f;
    float4 sl = ((const float4*)slow)[i];
    float4 o;
    o.x = 0.99f * sl.x + 0.01f * f.x;
    o.y = 0.99f * sl.y + 0.01f * f.y;
    o.z = 0.99f * sl.z + 0.01f * f.z;
    o.w = 0.99f * sl.w + 0.01f * f.w;
    ((float4*)outSlow)[i] = o;
}

extern "C" void kernel_launch(void* const* d_in, const int* in_sizes, int n_in,
                              void* d_out, int out_size, void* d_ws, size_t ws_size,
                              hipStream_t stream) {
    const float* x    = (const float*)d_in[0];
    const float* w    = (const float*)d_in[1];
    const float* fast = (const float*)d_in[2];
    const float* slow = (const float*)d_in[3];
    float* y       = (float*)d_out;
    float* outFast = y + (size_t)NTOK * DOUT;
    float* outSlow = outFast + (size_t)DOUT * DIN;

    char* ws = (char*)d_ws;
    double* scale = (double*)ws;                               // 32 KB
    float* norm2  = (float*)(ws + 32768);                      // 4 B (+pad)
    unsigned short* weff  = (unsigned short*)(ws + 32768 + 256);
    unsigned short* xbf   = weff + (size_t)DOUT * DIN;
    unsigned short* xT    = xbf + (size_t)NTOK * DIN;
    unsigned short* yactT = xT + (size_t)DIN * NTOK;
    // total ws use: ~33 KB + 4 * 33.55 MB = ~134 MB

    static bool s_attr = false;
    if (!s_attr) {
        hipFuncSetAttribute((const void*)gemm1_kernel,
                            hipFuncAttributeMaxDynamicSharedMemorySize, 135168);
        hipFuncSetAttribute((const void*)gemm2_kernel,
                            hipFuncAttributeMaxDynamicSharedMemorySize, 131072);
        s_attr = true;
    }

    hipMemsetAsync(norm2, 0, sizeof(float), stream);
    scale_kernel<<<4096, 256, 0, stream>>>(w, scale);
    weff_kernel<<<16384, 256, 0, stream>>>(w, fast, slow, scale, weff);
    transpose_kernel<<<dim3(128, 128), dim3(32, 8), 0, stream>>>(x, xbf, xT);
    gemm1_kernel<<<256, 512, 135168, stream>>>(xbf, weff, y, yactT);
    gemm2_kernel<<<256, 512, 131072, stream>>>(yactT, xT, fast, outFast, norm2);
    finalize_kernel<<<16384, 256, 0, stream>>>(slow, outFast, outSlow, norm2);
}